// Round 1
// baseline (492.588 us; speedup 1.0000x reference)
//
#include <hip/hip_runtime.h>
#include <hip/hip_bf16.h>

#define RMAX 40
#define LK   81
#define HH   512
#define WW   512
#define CC   3
#define BB   64

// ---------------------------------------------------------------------------
// Kernel A: per-sample weights (zero-padded, 128 floats/row), radius, and
// 3x3 channel-mix matrix (the C-axis conv collapsed through reflect-3).
// ---------------------------------------------------------------------------
__global__ void prep_kernel(const float* __restrict__ sigmas10,
                            const int* __restrict__ steps,
                            int* __restrict__ rbuf,
                            float* __restrict__ mbuf,   // [64][12] (3 rows of 4)
                            float* __restrict__ wbuf)   // [64][128], k at [16..96]
{
    int b = threadIdx.x;
    if (b >= BB) return;
    float sigma = sigmas10[steps[b]];
    int r = (int)floorf(4.0f * sigma + 0.5f);
    if (r > RMAX) r = RMAX;
    float s2 = sigma * sigma;

    float sum = 0.0f;
    for (int p = -r; p <= r; ++p)
        sum += expf(-0.5f * (float)(p * p) / s2);
    float inv = 1.0f / sum;

    // zero-padded weight row
    for (int i = 0; i < 128; ++i) wbuf[b * 128 + i] = 0.0f;
    for (int p = -r; p <= r; ++p)
        wbuf[b * 128 + 16 + (p + RMAX)] = expf(-0.5f * (float)(p * p) / s2) * inv;

    // channel-mix matrix: out[c] = sum_t k[t] * x[reflect3(c + t - 40)]
    float Mm[9];
    for (int i = 0; i < 9; ++i) Mm[i] = 0.0f;
    for (int p = -r; p <= r; ++p) {
        float wv = expf(-0.5f * (float)(p * p) / s2) * inv;
        for (int c = 0; c < CC; ++c) {
            int i = c + p;
            int j = ((i % 6) + 6) % 6;           // reflect for n=3 -> period 6
            int cc = (j < 3) ? j : 5 - j;
            Mm[c * 3 + cc] += wv;
        }
    }
    for (int c = 0; c < 3; ++c)
        for (int cc = 0; cc < 3; ++cc)
            mbuf[b * 12 + c * 4 + cc] = Mm[c * 3 + cc];
    rbuf[b] = r;
}

// ---------------------------------------------------------------------------
// Kernel B: fused channel mix + W-axis conv.  One block per (b,h) row.
// LDS holds 3 mixed, reflect-padded rows (592 floats each, 16B-aligned).
// Each thread produces 4 consecutive w outputs: 1 ds_read_b128 -> 16 FMAs.
// Edge taps handled by zero-padded weights (no predication).
// ---------------------------------------------------------------------------
__global__ __launch_bounds__(384) void passB_kernel(
    const float* __restrict__ x,
    const float* __restrict__ wbuf,
    const float* __restrict__ mbuf,
    const int*   __restrict__ rbuf,
    float* __restrict__ out1)
{
    __shared__ __align__(16) float mixed[CC][WW + 2 * RMAX]; // [3][592]

    const int b   = blockIdx.y;
    const int h   = blockIdx.x;
    const int tid = threadIdx.x;
    const int r   = __builtin_amdgcn_readfirstlane(rbuf[b]);

    const float M00 = mbuf[b * 12 + 0], M01 = mbuf[b * 12 + 1], M02 = mbuf[b * 12 + 2];
    const float M10 = mbuf[b * 12 + 4], M11 = mbuf[b * 12 + 5], M12 = mbuf[b * 12 + 6];
    const float M20 = mbuf[b * 12 + 8], M21 = mbuf[b * 12 + 9], M22 = mbuf[b * 12 + 10];

    const float* xb = x + (size_t)b * CC * HH * WW + (size_t)h * WW;

    // fill LDS: reflect-pad + channel mix
    for (int idx = tid; idx < WW + 2 * RMAX; idx += 384) {
        int i  = idx - RMAX;                 // logical position -40..551
        int jm = i & (2 * WW - 1);           // mod 1024 (works for negatives)
        int src = (jm < WW) ? jm : (2 * WW - 1 - jm);
        float x0 = xb[src];
        float x1 = xb[HH * WW + src];
        float x2 = xb[2 * HH * WW + src];
        mixed[0][idx] = M00 * x0 + M01 * x1 + M02 * x2;
        mixed[1][idx] = M10 * x0 + M11 * x1 + M12 * x2;
        mixed[2][idx] = M20 * x0 + M21 * x1 + M22 * x2;
    }
    __syncthreads();

    const int c  = tid >> 7;        // 0..2
    const int g  = tid & 127;
    const int w0 = g << 2;          // 4 outputs per thread

    const int t0    = (RMAX - r) & ~3;                  // aligned first tap
    const int n4    = ((r + RMAX + 3 - t0) >> 2) + 1;   // float4 iterations
    const int dbase = (w0 + t0) >> 2;
    const int kbase = (16 + t0) >> 2;

    const float4* D4 = (const float4*)(&mixed[c][0]);
    const float4* K4 = (const float4*)(wbuf + b * 128);

    float4 Wlo = K4[kbase - 1];
    float acc0 = 0.f, acc1 = 0.f, acc2 = 0.f, acc3 = 0.f;

    for (int s = 0; s < n4; ++s) {
        float4 Whi = K4[kbase + s];     // uniform -> scalar load
        float4 D   = D4[dbase + s];     // ds_read_b128, conflict-free
        // acc[j] += k_hat[16 + t0 + 4s + u - j] * D[u]
        acc0 += Whi.x * D.x; acc1 += Wlo.w * D.x; acc2 += Wlo.z * D.x; acc3 += Wlo.y * D.x;
        acc0 += Whi.y * D.y; acc1 += Whi.x * D.y; acc2 += Wlo.w * D.y; acc3 += Wlo.z * D.y;
        acc0 += Whi.z * D.z; acc1 += Whi.y * D.z; acc2 += Whi.x * D.z; acc3 += Wlo.w * D.z;
        acc0 += Whi.w * D.w; acc1 += Whi.z * D.w; acc2 += Whi.y * D.w; acc3 += Whi.x * D.w;
        Wlo = Whi;
    }

    float4 o; o.x = acc0; o.y = acc1; o.z = acc2; o.w = acc3;
    float* dst = out1 + ((size_t)b * CC + c) * HH * WW + (size_t)h * WW + w0;
    *(float4*)dst = o;
}

// ---------------------------------------------------------------------------
// Kernel C: H-axis conv. Lanes along w (coalesced); 16 consecutive h outputs
// per thread via a 16-deep register ring buffer, inner t-loop unrolled x16 so
// ring indices are static. Rounded-up trip count covered by zero weights.
// ---------------------------------------------------------------------------
__device__ __forceinline__ int refl512(int i) {
    int jm = i & (2 * HH - 1);              // mod 1024, ok for i >= -1024
    return (jm < HH) ? jm : (2 * HH - 1 - jm);
}

__global__ __launch_bounds__(256) void passC_kernel(
    const float* __restrict__ in1,
    const float* __restrict__ wbuf,
    const int*   __restrict__ rbuf,
    float* __restrict__ out)
{
    const int tid = threadIdx.x;
    const int w   = blockIdx.x * 256 + tid;
    const int h0  = blockIdx.y * 16;
    const int bc  = blockIdx.z;             // b*3 + c
    const int b   = bc / 3;
    const int r   = __builtin_amdgcn_readfirstlane(rbuf[b]);

    const float* src = in1 + (size_t)bc * HH * WW;
    const float* kw  = wbuf + b * 128;

    float acc[16];
    float D[16];
#pragma unroll
    for (int j = 0; j < 16; ++j) acc[j] = 0.0f;

    // prologue: rows h0 - r .. h0 - r + 15
#pragma unroll
    for (int q = 0; q < 16; ++q)
        D[q] = src[(size_t)refl512(h0 - r + q) * WW + w];

    const int Mr = (2 * r + 16) & ~15;      // ceil((2r+1)/16)*16

    for (int c0 = 0; c0 < Mr; c0 += 16) {
#pragma unroll
        for (int u = 0; u < 16; ++u) {
            int m = c0 + u;
            float wgt = kw[16 + RMAX - r + m];   // zero beyond 2r -> harmless
#pragma unroll
            for (int j = 0; j < 16; ++j)
                acc[j] += wgt * D[(u + j) & 15];
            // refill slot m&15 (=u) with row h0 - r + m + 16 (prefetch dist 16)
            D[u] = src[(size_t)refl512(h0 - r + m + 16) * WW + w];
        }
    }

    float* dst = out + (size_t)bc * HH * WW + (size_t)h0 * WW + w;
#pragma unroll
    for (int j = 0; j < 16; ++j)
        __builtin_nontemporal_store(acc[j], dst + (size_t)j * WW);
}

// ---------------------------------------------------------------------------
extern "C" void kernel_launch(void* const* d_in, const int* in_sizes, int n_in,
                              void* d_out, int out_size, void* d_ws, size_t ws_size,
                              hipStream_t stream)
{
    const float* x      = (const float*)d_in[0];
    const float* sigmas = (const float*)d_in[1];
    const int*   steps  = (const int*)d_in[2];
    float*       out    = (float*)d_out;

    // workspace layout
    int*   rbuf  = (int*)d_ws;                            // 256 B
    float* mbuf  = (float*)((char*)d_ws + 256);           // 3 KB
    float* wbuf  = (float*)((char*)d_ws + 4096);          // 32 KB
    float* inter = (float*)((char*)d_ws + 65536);         // 192 MiB

    prep_kernel<<<1, 64, 0, stream>>>(sigmas, steps, rbuf, mbuf, wbuf);

    dim3 gB(HH, BB);
    passB_kernel<<<gB, 384, 0, stream>>>(x, wbuf, mbuf, rbuf, inter);

    dim3 gC(WW / 256, HH / 16, BB * CC);
    passC_kernel<<<gC, 256, 0, stream>>>(inter, wbuf, rbuf, out);
}

// Round 2
// 469.592 us; speedup vs baseline: 1.0490x; 1.0490x over previous
//
#include <hip/hip_runtime.h>
#include <hip/hip_bf16.h>

#define RMAX 40
#define LK   81
#define HH   512
#define WW   512
#define CC   3
#define BB   64
#define ROWS 2   // h-rows per passB block

// ---------------------------------------------------------------------------
// Kernel A: per-sample weights (zero-padded, 128 floats/row), radius, and
// 3x3 channel-mix matrix (the C-axis conv collapsed through reflect-3).
// ---------------------------------------------------------------------------
__global__ void prep_kernel(const float* __restrict__ sigmas10,
                            const int* __restrict__ steps,
                            int* __restrict__ rbuf,
                            float* __restrict__ mbuf,   // [64][12] (3 rows of 4)
                            float* __restrict__ wbuf)   // [64][128], k at [16..96]
{
    int b = threadIdx.x;
    if (b >= BB) return;
    float sigma = sigmas10[steps[b]];
    int r = (int)floorf(4.0f * sigma + 0.5f);
    if (r > RMAX) r = RMAX;
    float s2 = sigma * sigma;

    float sum = 0.0f;
    for (int p = -r; p <= r; ++p)
        sum += expf(-0.5f * (float)(p * p) / s2);
    float inv = 1.0f / sum;

    for (int i = 0; i < 128; ++i) wbuf[b * 128 + i] = 0.0f;
    for (int p = -r; p <= r; ++p)
        wbuf[b * 128 + 16 + (p + RMAX)] = expf(-0.5f * (float)(p * p) / s2) * inv;

    // channel-mix matrix: out[c] = sum_t k[t] * x[reflect3(c + t - 40)]
    float Mm[9];
    for (int i = 0; i < 9; ++i) Mm[i] = 0.0f;
    for (int p = -r; p <= r; ++p) {
        float wv = expf(-0.5f * (float)(p * p) / s2) * inv;
        for (int c = 0; c < CC; ++c) {
            int i = c + p;
            int j = ((i % 6) + 6) % 6;           // reflect for n=3 -> period 6
            int cc = (j < 3) ? j : 5 - j;
            Mm[c * 3 + cc] += wv;
        }
    }
    for (int c = 0; c < 3; ++c)
        for (int cc = 0; cc < 3; ++cc)
            mbuf[b * 12 + c * 4 + cc] = Mm[c * 3 + cc];
    rbuf[b] = r;
}

// ---------------------------------------------------------------------------
// Kernel B: fused channel mix + W-axis conv.  One block per (b, 2 h-rows).
// 256 threads; 18 independent global loads in flight per thread during
// staging; LDS 14.2 KB -> 8 blocks/CU (100% wave occupancy); 3 compute
// tasks/thread, each: 1 ds_read_b128 -> 16 FMAs per float4 of taps.
// Edge taps handled by zero-padded weights. x loads nontemporal to keep
// LLC for the intermediate that passC re-reads.
// ---------------------------------------------------------------------------
__global__ __launch_bounds__(256) void passB_kernel(
    const float* __restrict__ x,
    const float* __restrict__ wbuf,
    const float* __restrict__ mbuf,
    const int*   __restrict__ rbuf,
    float* __restrict__ out1)
{
    __shared__ __align__(16) float mixed[CC * ROWS][WW + 2 * RMAX]; // [6][592]

    const int b   = blockIdx.y;
    const int h0  = blockIdx.x * ROWS;
    const int tid = threadIdx.x;
    const int r   = __builtin_amdgcn_readfirstlane(rbuf[b]);

    const float M00 = mbuf[b * 12 + 0], M01 = mbuf[b * 12 + 1], M02 = mbuf[b * 12 + 2];
    const float M10 = mbuf[b * 12 + 4], M11 = mbuf[b * 12 + 5], M12 = mbuf[b * 12 + 6];
    const float M20 = mbuf[b * 12 + 8], M21 = mbuf[b * 12 + 9], M22 = mbuf[b * 12 + 10];

    const float* xb = x + (size_t)b * CC * HH * WW + (size_t)h0 * WW;

    for (int idx = tid; idx < WW + 2 * RMAX; idx += 256) {
        int i  = idx - RMAX;                 // logical position -40..551
        int jm = i & (2 * WW - 1);           // mod 1024 (works for negatives)
        int src = (jm < WW) ? jm : (2 * WW - 1 - jm);
        float a0 = __builtin_nontemporal_load(xb + src);
        float a1 = __builtin_nontemporal_load(xb + HH * WW + src);
        float a2 = __builtin_nontemporal_load(xb + 2 * HH * WW + src);
        float b0 = __builtin_nontemporal_load(xb + WW + src);
        float b1 = __builtin_nontemporal_load(xb + HH * WW + WW + src);
        float b2 = __builtin_nontemporal_load(xb + 2 * HH * WW + WW + src);
        mixed[0][idx] = M00 * a0 + M01 * a1 + M02 * a2;  // c=0,row=0
        mixed[1][idx] = M00 * b0 + M01 * b1 + M02 * b2;  // c=0,row=1
        mixed[2][idx] = M10 * a0 + M11 * a1 + M12 * a2;  // c=1,row=0
        mixed[3][idx] = M10 * b0 + M11 * b1 + M12 * b2;  // c=1,row=1
        mixed[4][idx] = M20 * a0 + M21 * a1 + M22 * a2;  // c=2,row=0
        mixed[5][idx] = M20 * b0 + M21 * b1 + M22 * b2;  // c=2,row=1
    }
    __syncthreads();

    const int t0    = (RMAX - r) & ~3;                  // aligned first tap
    const int n4    = ((r + RMAX + 3 - t0) >> 2) + 1;   // float4 iterations
    const int kbase = (16 + t0) >> 2;
    const float4* K4 = (const float4*)(wbuf + b * 128);

#pragma unroll
    for (int k = 0; k < 3; ++k) {
        const int task = tid + 256 * k;     // 0..767
        const int g    = task & 127;
        const int rc   = task >> 7;         // 0..5  (c = rc>>1, row = rc&1)
        const int w0   = g << 2;

        const int dbase = (w0 + t0) >> 2;
        const float4* D4 = (const float4*)(&mixed[rc][0]);

        float4 Wlo = K4[kbase - 1];
        float acc0 = 0.f, acc1 = 0.f, acc2 = 0.f, acc3 = 0.f;

        for (int s = 0; s < n4; ++s) {
            float4 Whi = K4[kbase + s];     // uniform -> scalar load
            float4 D   = D4[dbase + s];     // ds_read_b128, conflict-free
            acc0 += Whi.x * D.x; acc1 += Wlo.w * D.x; acc2 += Wlo.z * D.x; acc3 += Wlo.y * D.x;
            acc0 += Whi.y * D.y; acc1 += Whi.x * D.y; acc2 += Wlo.w * D.y; acc3 += Wlo.z * D.y;
            acc0 += Whi.z * D.z; acc1 += Whi.y * D.z; acc2 += Whi.x * D.z; acc3 += Wlo.w * D.z;
            acc0 += Whi.w * D.w; acc1 += Whi.z * D.w; acc2 += Whi.y * D.w; acc3 += Whi.x * D.w;
            Wlo = Whi;
        }

        float4 o; o.x = acc0; o.y = acc1; o.z = acc2; o.w = acc3;
        const int c = rc >> 1, row = rc & 1;
        float* dst = out1 + ((size_t)b * CC + c) * HH * WW
                   + (size_t)(h0 + row) * WW + w0;
        *(float4*)dst = o;
    }
}

// ---------------------------------------------------------------------------
// Kernel C: H-axis conv. Lanes along w (coalesced); 16 consecutive h outputs
// per thread via a 16-deep register ring buffer, inner t-loop unrolled x16 so
// ring indices are static. Rounded-up trip count covered by zero weights.
// ---------------------------------------------------------------------------
__device__ __forceinline__ int refl512(int i) {
    int jm = i & (2 * HH - 1);              // mod 1024, ok for i >= -1024
    return (jm < HH) ? jm : (2 * HH - 1 - jm);
}

__global__ __launch_bounds__(256) void passC_kernel(
    const float* __restrict__ in1,
    const float* __restrict__ wbuf,
    const int*   __restrict__ rbuf,
    float* __restrict__ out)
{
    const int tid = threadIdx.x;
    const int w   = blockIdx.x * 256 + tid;
    const int h0  = blockIdx.y * 16;
    const int bc  = blockIdx.z;             // b*3 + c
    const int b   = bc / 3;
    const int r   = __builtin_amdgcn_readfirstlane(rbuf[b]);

    const float* src = in1 + (size_t)bc * HH * WW;
    const float* kw  = wbuf + b * 128;

    float acc[16];
    float D[16];
#pragma unroll
    for (int j = 0; j < 16; ++j) acc[j] = 0.0f;

#pragma unroll
    for (int q = 0; q < 16; ++q)
        D[q] = src[(size_t)refl512(h0 - r + q) * WW + w];

    const int Mr = (2 * r + 16) & ~15;      // ceil((2r+1)/16)*16

    for (int c0 = 0; c0 < Mr; c0 += 16) {
#pragma unroll
        for (int u = 0; u < 16; ++u) {
            int m = c0 + u;
            float wgt = kw[16 + RMAX - r + m];   // zero beyond 2r -> harmless
#pragma unroll
            for (int j = 0; j < 16; ++j)
                acc[j] += wgt * D[(u + j) & 15];
            D[u] = src[(size_t)refl512(h0 - r + m + 16) * WW + w];
        }
    }

    float* dst = out + (size_t)bc * HH * WW + (size_t)h0 * WW + w;
#pragma unroll
    for (int j = 0; j < 16; ++j)
        __builtin_nontemporal_store(acc[j], dst + (size_t)j * WW);
}

// ---------------------------------------------------------------------------
extern "C" void kernel_launch(void* const* d_in, const int* in_sizes, int n_in,
                              void* d_out, int out_size, void* d_ws, size_t ws_size,
                              hipStream_t stream)
{
    const float* x      = (const float*)d_in[0];
    const float* sigmas = (const float*)d_in[1];
    const int*   steps  = (const int*)d_in[2];
    float*       out    = (float*)d_out;

    int*   rbuf  = (int*)d_ws;                            // 256 B
    float* mbuf  = (float*)((char*)d_ws + 256);           // 3 KB
    float* wbuf  = (float*)((char*)d_ws + 4096);          // 32 KB
    float* inter = (float*)((char*)d_ws + 65536);         // 192 MiB

    prep_kernel<<<1, 64, 0, stream>>>(sigmas, steps, rbuf, mbuf, wbuf);

    dim3 gB(HH / ROWS, BB);
    passB_kernel<<<gB, 256, 0, stream>>>(x, wbuf, mbuf, rbuf, inter);

    dim3 gC(WW / 256, HH / 16, BB * CC);
    passC_kernel<<<gC, 256, 0, stream>>>(inter, wbuf, rbuf, out);
}

// Round 3
// 423.123 us; speedup vs baseline: 1.1642x; 1.1098x over previous
//
#include <hip/hip_runtime.h>
#include <hip/hip_bf16.h>

#define RMAX 40
#define LK   81
#define HH   512
#define WW   512
#define CC   3
#define BB   64
#define ROWS 2    // h-rows per passB block
#define TH   32   // h-outputs per passC thread (ring depth)

typedef unsigned short u16;

// bf16 round-to-nearest-even pack/unpack (values here are finite, no NaN)
__device__ __forceinline__ u16 f2bf(float f) {
    unsigned u = __float_as_uint(f);
    u += 0x7FFFu + ((u >> 16) & 1u);
    return (u16)(u >> 16);
}
__device__ __forceinline__ float bf2f(u16 s) {
    return __uint_as_float(((unsigned)s) << 16);
}

// ---------------------------------------------------------------------------
// Kernel A: per-sample weights (zero-padded, 128 floats/row), radius, and
// 3x3 channel-mix matrix (the C-axis conv collapsed through reflect-3).
// ---------------------------------------------------------------------------
__global__ void prep_kernel(const float* __restrict__ sigmas10,
                            const int* __restrict__ steps,
                            int* __restrict__ rbuf,
                            float* __restrict__ mbuf,   // [64][12]
                            float* __restrict__ wbuf)   // [64][128], k at [16..96]
{
    int b = threadIdx.x;
    if (b >= BB) return;
    float sigma = sigmas10[steps[b]];
    int r = (int)floorf(4.0f * sigma + 0.5f);
    if (r > RMAX) r = RMAX;
    float s2 = sigma * sigma;

    float sum = 0.0f;
    for (int p = -r; p <= r; ++p)
        sum += expf(-0.5f * (float)(p * p) / s2);
    float inv = 1.0f / sum;

    for (int i = 0; i < 128; ++i) wbuf[b * 128 + i] = 0.0f;
    for (int p = -r; p <= r; ++p)
        wbuf[b * 128 + 16 + (p + RMAX)] = expf(-0.5f * (float)(p * p) / s2) * inv;

    // channel-mix matrix: out[c] = sum_t k[t] * x[reflect3(c + t - 40)]
    float Mm[9];
    for (int i = 0; i < 9; ++i) Mm[i] = 0.0f;
    for (int p = -r; p <= r; ++p) {
        float wv = expf(-0.5f * (float)(p * p) / s2) * inv;
        for (int c = 0; c < CC; ++c) {
            int i = c + p;
            int j = ((i % 6) + 6) % 6;           // reflect for n=3 -> period 6
            int cc = (j < 3) ? j : 5 - j;
            Mm[c * 3 + cc] += wv;
        }
    }
    for (int c = 0; c < 3; ++c)
        for (int cc = 0; cc < 3; ++cc)
            mbuf[b * 12 + c * 4 + cc] = Mm[c * 3 + cc];
    rbuf[b] = r;
}

// ---------------------------------------------------------------------------
// Kernel B: fused channel mix + W-axis conv, bf16 output.
// One block per (b, 2 h-rows), 256 threads, LDS 14.2 KB -> 8 blocks/CU.
// Staging: 18 independent nontemporal loads in flight/thread. Compute: 3
// tasks/thread, each 1 ds_read_b128 -> 16 FMAs per float4 of taps.
// Intermediate stored bf16 with regular stores (keep it resident in LLC
// for passC's amplified re-reads).
// ---------------------------------------------------------------------------
__global__ __launch_bounds__(256) void passB_kernel(
    const float* __restrict__ x,
    const float* __restrict__ wbuf,
    const float* __restrict__ mbuf,
    const int*   __restrict__ rbuf,
    u16* __restrict__ out1)
{
    __shared__ __align__(16) float mixed[CC * ROWS][WW + 2 * RMAX]; // [6][592]

    const int b   = blockIdx.y;
    const int h0  = blockIdx.x * ROWS;
    const int tid = threadIdx.x;
    const int r   = __builtin_amdgcn_readfirstlane(rbuf[b]);

    const float M00 = mbuf[b * 12 + 0], M01 = mbuf[b * 12 + 1], M02 = mbuf[b * 12 + 2];
    const float M10 = mbuf[b * 12 + 4], M11 = mbuf[b * 12 + 5], M12 = mbuf[b * 12 + 6];
    const float M20 = mbuf[b * 12 + 8], M21 = mbuf[b * 12 + 9], M22 = mbuf[b * 12 + 10];

    const float* xb = x + (size_t)b * CC * HH * WW + (size_t)h0 * WW;

    for (int idx = tid; idx < WW + 2 * RMAX; idx += 256) {
        int i  = idx - RMAX;                 // logical position -40..551
        int jm = i & (2 * WW - 1);           // mod 1024 (ok for negatives)
        int src = (jm < WW) ? jm : (2 * WW - 1 - jm);
        float a0 = __builtin_nontemporal_load(xb + src);
        float a1 = __builtin_nontemporal_load(xb + HH * WW + src);
        float a2 = __builtin_nontemporal_load(xb + 2 * HH * WW + src);
        float b0 = __builtin_nontemporal_load(xb + WW + src);
        float b1 = __builtin_nontemporal_load(xb + HH * WW + WW + src);
        float b2 = __builtin_nontemporal_load(xb + 2 * HH * WW + WW + src);
        mixed[0][idx] = M00 * a0 + M01 * a1 + M02 * a2;  // c=0,row=0
        mixed[1][idx] = M00 * b0 + M01 * b1 + M02 * b2;  // c=0,row=1
        mixed[2][idx] = M10 * a0 + M11 * a1 + M12 * a2;  // c=1,row=0
        mixed[3][idx] = M10 * b0 + M11 * b1 + M12 * b2;  // c=1,row=1
        mixed[4][idx] = M20 * a0 + M21 * a1 + M22 * a2;  // c=2,row=0
        mixed[5][idx] = M20 * b0 + M21 * b1 + M22 * b2;  // c=2,row=1
    }
    __syncthreads();

    const int t0    = (RMAX - r) & ~3;                  // aligned first tap
    const int n4    = ((r + RMAX + 3 - t0) >> 2) + 1;   // float4 iterations
    const int kbase = (16 + t0) >> 2;
    const float4* K4 = (const float4*)(wbuf + b * 128);

#pragma unroll
    for (int k = 0; k < 3; ++k) {
        const int task = tid + 256 * k;     // 0..767
        const int g    = task & 127;
        const int rc   = task >> 7;         // 0..5  (c = rc>>1, row = rc&1)
        const int w0   = g << 2;

        const int dbase = (w0 + t0) >> 2;
        const float4* D4 = (const float4*)(&mixed[rc][0]);

        float4 Wlo = K4[kbase - 1];
        float acc0 = 0.f, acc1 = 0.f, acc2 = 0.f, acc3 = 0.f;

        for (int s = 0; s < n4; ++s) {
            float4 Whi = K4[kbase + s];     // uniform -> scalar load
            float4 D   = D4[dbase + s];     // ds_read_b128, conflict-free
            acc0 += Whi.x * D.x; acc1 += Wlo.w * D.x; acc2 += Wlo.z * D.x; acc3 += Wlo.y * D.x;
            acc0 += Whi.y * D.y; acc1 += Whi.x * D.y; acc2 += Wlo.w * D.y; acc3 += Wlo.z * D.y;
            acc0 += Whi.z * D.z; acc1 += Whi.y * D.z; acc2 += Whi.x * D.z; acc3 += Wlo.w * D.z;
            acc0 += Whi.w * D.w; acc1 += Whi.z * D.w; acc2 += Whi.y * D.w; acc3 += Whi.x * D.w;
            Wlo = Whi;
        }

        ushort4 o;
        o.x = f2bf(acc0); o.y = f2bf(acc1); o.z = f2bf(acc2); o.w = f2bf(acc3);
        const int c = rc >> 1, row = rc & 1;
        u16* dst = out1 + ((size_t)b * CC + c) * HH * WW
                 + (size_t)(h0 + row) * WW + w0;
        *(ushort4*)dst = o;                  // 8B aligned (w0 % 4 == 0)
    }
}

// ---------------------------------------------------------------------------
// Kernel C: H-axis conv from bf16 intermediate. Lanes along w (coalesced);
// 32 consecutive h outputs per thread via a 32-deep register ring, t-loop
// unrolled x32 so ring indices are static. Read amplification (2r+32)/32,
// mostly LLC hits (100 MB intermediate << 256 MiB LLC). Zero-padded weights
// cover the rounded-up trip count (max weight index 127 fits the 128-row).
// ---------------------------------------------------------------------------
__device__ __forceinline__ int refl512(int i) {
    int jm = i & (2 * HH - 1);              // mod 1024, ok for i >= -1024
    return (jm < HH) ? jm : (2 * HH - 1 - jm);
}

__global__ __launch_bounds__(256) void passC_kernel(
    const u16* __restrict__ in1,
    const float* __restrict__ wbuf,
    const int*   __restrict__ rbuf,
    float* __restrict__ out)
{
    const int tid = threadIdx.x;
    const int w   = blockIdx.x * 256 + tid;
    const int h0  = blockIdx.y * TH;
    const int bc  = blockIdx.z;             // b*3 + c
    const int b   = bc / 3;
    const int r   = __builtin_amdgcn_readfirstlane(rbuf[b]);

    const u16*  src = in1 + (size_t)bc * HH * WW;
    const float* kw  = wbuf + b * 128;

    float acc[TH];
    float D[TH];
#pragma unroll
    for (int j = 0; j < TH; ++j) acc[j] = 0.0f;

#pragma unroll
    for (int q = 0; q < TH; ++q)
        D[q] = bf2f(src[(size_t)refl512(h0 - r + q) * WW + w]);

    const int Mr = (2 * r + TH) & ~(TH - 1);   // ceil((2r+1)/TH)*TH

    for (int c0 = 0; c0 < Mr; c0 += TH) {
#pragma unroll
        for (int u = 0; u < TH; ++u) {
            int m = c0 + u;
            float wgt = kw[16 + RMAX - r + m];   // zero beyond 2r -> harmless
#pragma unroll
            for (int j = 0; j < TH; ++j)
                acc[j] += wgt * D[(u + j) & (TH - 1)];
            // refill slot u with row h0 - r + m + TH (prefetch distance TH)
            D[u] = bf2f(src[(size_t)refl512(h0 - r + m + TH) * WW + w]);
        }
    }

    float* dst = out + (size_t)bc * HH * WW + (size_t)h0 * WW + w;
#pragma unroll
    for (int j = 0; j < TH; ++j)
        __builtin_nontemporal_store(acc[j], dst + (size_t)j * WW);
}

// ---------------------------------------------------------------------------
extern "C" void kernel_launch(void* const* d_in, const int* in_sizes, int n_in,
                              void* d_out, int out_size, void* d_ws, size_t ws_size,
                              hipStream_t stream)
{
    const float* x      = (const float*)d_in[0];
    const float* sigmas = (const float*)d_in[1];
    const int*   steps  = (const int*)d_in[2];
    float*       out    = (float*)d_out;

    int*   rbuf  = (int*)d_ws;                            // 256 B
    float* mbuf  = (float*)((char*)d_ws + 256);           // 3 KB
    float* wbuf  = (float*)((char*)d_ws + 4096);          // 32 KB
    u16*   inter = (u16*)((char*)d_ws + 65536);           // 96 MiB bf16

    prep_kernel<<<1, 64, 0, stream>>>(sigmas, steps, rbuf, mbuf, wbuf);

    dim3 gB(HH / ROWS, BB);
    passB_kernel<<<gB, 256, 0, stream>>>(x, wbuf, mbuf, rbuf, inter);

    dim3 gC(WW / 256, HH / TH, BB * CC);
    passC_kernel<<<gC, 256, 0, stream>>>(inter, wbuf, rbuf, out);
}